// Round 18
// baseline (286.807 us; speedup 1.0000x reference)
//
#include <hip/hip_runtime.h>
#include <stdint.h>

#define NN   100000
#define NE   1600000
#define NG   512
#define HID  128
#define NOUT 64
#define BK   128
#define BKSH 7
#define NBUK ((NN + BK - 1) / BK)      // 782 buckets of 128 nodes
#define AHIST_E 4096
#define NAH  ((NE + AHIST_E - 1) / AHIST_E)   // 391
#define CHUNK 8192
#define NSC  ((NE + CHUNK - 1) / CHUNK)       // 196

typedef __bf16 bf16_t;
typedef bf16_t bf16x8 __attribute__((ext_vector_type(8)));
typedef float  f32x4  __attribute__((ext_vector_type(4)));
typedef unsigned int u32;
typedef u32 u32x2 __attribute__((ext_vector_type(2)));
typedef u32 u32x4 __attribute__((ext_vector_type(4)));
typedef unsigned short u16;

struct __align__(8) EdgeT { int d, s; };

__device__ __forceinline__ u16 f2b(float f) {
    union { float f; u32 u; } v; v.f = f;
    u32 u = v.u + 0x7fffu + ((v.u >> 16) & 1u);   // RNE
    return (u16)(u >> 16);
}
__device__ __forceinline__ float blo(u32 u) {
    union { u32 u; float f; } v; v.u = u << 16; return v.f;
}
__device__ __forceinline__ float bhi(u32 u) {
    union { u32 u; float f; } v; v.u = u & 0xffff0000u; return v.f;
}

// ---------------- CSR build, bucketed (BK=128) ----------------
__global__ __launch_bounds__(256) void k_bhist(const int* __restrict__ dst,
                                               int* __restrict__ bcnt) {
    __shared__ int h[NBUK];
    int t = threadIdx.x;
    for (int i = t; i < NBUK; i += 256) h[i] = 0;
    __syncthreads();
    int e0 = blockIdx.x * AHIST_E;
    int e1 = min(NE, e0 + AHIST_E);
    for (int e = e0 + t; e < e1; e += 256) atomicAdd(&h[dst[e] >> BKSH], 1);
    __syncthreads();
    for (int i = t; i < NBUK; i += 256) if (h[i]) atomicAdd(&bcnt[i], h[i]);
}

__global__ __launch_bounds__(256) void k_bscan(const int* __restrict__ bcnt,
                                               int* __restrict__ boff, int* __restrict__ gcur,
                                               int* __restrict__ rpN) {
    __shared__ int sh[256];
    int t = threadIdx.x;
    int v[4]; int s = 0;
#pragma unroll
    for (int j = 0; j < 4; j++) {
        int idx = t * 4 + j;
        v[j] = (idx < NBUK) ? bcnt[idx] : 0;
        s += v[j];
    }
    sh[t] = s; __syncthreads();
    for (int off = 1; off < 256; off <<= 1) {
        int x = (t >= off) ? sh[t - off] : 0;
        __syncthreads();
        sh[t] += x;
        __syncthreads();
    }
    int run = sh[t] - s;
#pragma unroll
    for (int j = 0; j < 4; j++) {
        int idx = t * 4 + j;
        if (idx < NBUK) { boff[idx] = run; gcur[idx] = run; }
        run += v[j];
    }
    if (t == 255) { boff[NBUK] = NE; rpN[0] = NE; }
}

__global__ __launch_bounds__(256) void k_scatter(const int* __restrict__ src,
                                                 const int* __restrict__ dst,
                                                 int* __restrict__ gcur,
                                                 EdgeT* __restrict__ ebuf) {
    __shared__ int hist[NBUK], base[NBUK];
    int t = threadIdx.x;
    for (int i = t; i < NBUK; i += 256) hist[i] = 0;
    __syncthreads();
    int e0 = blockIdx.x * CHUNK;
    int e1 = min(NE, e0 + CHUNK);
    for (int e = e0 + t; e < e1; e += 256) atomicAdd(&hist[dst[e] >> BKSH], 1);
    __syncthreads();
    for (int i = t; i < NBUK; i += 256) {
        int h = hist[i];
        base[i] = h ? atomicAdd(&gcur[i], h) : 0;
        hist[i] = 0;
    }
    __syncthreads();
    for (int e = e0 + t; e < e1; e += 256) {
        int d = dst[e], bk = d >> BKSH;
        int r = atomicAdd(&hist[bk], 1);
        EdgeT p; p.d = d; p.s = src[e];
        ebuf[base[bk] + r] = p;
    }
}

__global__ __launch_bounds__(256) void k_bucketc(const EdgeT* __restrict__ ebuf,
                                                 const int* __restrict__ boff,
                                                 int* __restrict__ rp, float* __restrict__ dinv,
                                                 int* __restrict__ col) {
    __shared__ int cnt[BK], pos[BK], run[BK], s2[64];
    int b = blockIdx.x, t = threadIdx.x;
    int d0 = b * BK;
    int e0 = boff[b], e1 = boff[b + 1];
    for (int i = t; i < BK; i += 256) { cnt[i] = 0; run[i] = 0; }
    __syncthreads();
    for (int e = e0 + t; e < e1; e += 256) atomicAdd(&cnt[ebuf[e].d - d0], 1);
    __syncthreads();
    for (int i = t; i < BK; i += 256) {
        int v = d0 + i;
        if (v < NN) dinv[v] = rsqrtf((float)(cnt[i] + 1));
    }
    int c0 = 0, c1 = 0, s = 0;
    if (t < 64) {
        c0 = cnt[2 * t]; c1 = cnt[2 * t + 1];
        s = c0 + c1; s2[t] = s;
    }
    __syncthreads();
    for (int off = 1; off < 64; off <<= 1) {
        int x = (t >= off && t < 64) ? s2[t - off] : 0;
        __syncthreads();
        if (t < 64) s2[t] += x;
        __syncthreads();
    }
    if (t < 64) {
        int bse = s2[t] - s;
        pos[2 * t] = bse; pos[2 * t + 1] = bse + c0;
    }
    __syncthreads();
    for (int i = t; i < BK; i += 256) {
        int v = d0 + i;
        if (v < NN) rp[v] = e0 + pos[i];
    }
    for (int e = e0 + t; e < e1; e += 256) {
        EdgeT p = ebuf[e];
        int i = p.d - d0;
        int r = atomicAdd(&run[i], 1);
        col[e0 + pos[i] + r] = p.s;
    }
}

// ---------------- fused weight prep + cntg ----------------
// tid<2048: pack W1;  [2048,10240): Wcp = bf16(W2@Wfc) packed;
// [10240,10304): bc;  [10304,10816): cntg via binary search on sorted batch.
__global__ void k_wprep(const float* __restrict__ W1, u16* __restrict__ Wp,
                        const float* __restrict__ W2, const float* __restrict__ Wfc,
                        const float* __restrict__ b2, const float* __restrict__ bfc,
                        u16* __restrict__ Wcp, float* __restrict__ bc,
                        const int* __restrict__ batch, int* __restrict__ cntg) {
    int tid = blockIdx.x * blockDim.x + threadIdx.x;
    if (tid < 2048) {
        int f = tid >> 6, l = tid & 63;
        int c = f >> 2, s = f & 3;
        int n  = (l & 15) * 8 + c;
        int k0 = s * 32 + ((l >> 4) << 3);
#pragma unroll
        for (int j = 0; j < 8; j++) Wp[tid * 8 + j] = f2b(W1[(k0 + j) * HID + n]);
    } else if (tid < 2048 + HID * NOUT) {
        int t2 = tid - 2048;
        int k = t2 >> 6, n = t2 & 63;
        float a = 0.f;
        for (int m = 0; m < HID; m++) a += W2[k * HID + m] * Wfc[m * NOUT + n];
        int s = k >> 5, lh = (k >> 3) & 3, j = k & 7;
        int c = n & 3, l15 = n >> 2;
        int l = (lh << 4) | l15, f = c * 4 + s;
        Wcp[((f * 64 + l) << 3) + j] = f2b(a);
    } else if (tid < 2048 + HID * NOUT + NOUT) {
        int o = tid - 2048 - HID * NOUT;
        float a = bfc[o];
        for (int k = 0; k < HID; k++) a += b2[k] * Wfc[k * NOUT + o];
        bc[o] = a;
    } else if (tid < 2048 + HID * NOUT + NOUT + NG) {
        int g = tid - 2048 - HID * NOUT - NOUT;
        int lo0 = 0, hi0 = NN;
        while (lo0 < hi0) { int mid = (lo0 + hi0) >> 1; if (batch[mid] < g) lo0 = mid + 1; else hi0 = mid; }
        int lo1 = lo0, hi1 = NN;
        while (lo1 < hi1) { int mid = (lo1 + hi1) >> 1; if (batch[mid] < g + 1) lo1 = mid + 1; else hi1 = mid; }
        cntg[g] = lo1 - lo0;
    }
}

// ---------------- GEMM1: g = bf16((X @ W1) * dinv[row]), [NN][128] ----------------
__global__ __launch_bounds__(256) void k_gemm(const float* __restrict__ Xf,
                                              const u16* __restrict__ Wp,
                                              const float* __restrict__ dinv,
                                              u16* __restrict__ Gout) {
    int w = threadIdx.x >> 6, l = threadIdx.x & 63;
    int r0  = blockIdx.x * 64 + w * 16;
    int l15 = l & 15, lh = l >> 4;
    int arow = r0 + l15;
    int arc  = (arow < NN) ? arow : (NN - 1);

    f32x4 acc[8];
#pragma unroll
    for (int c = 0; c < 8; c++) acc[c] = (f32x4){0.f, 0.f, 0.f, 0.f};

#pragma unroll
    for (int s = 0; s < 4; s++) {
        int k0 = s * 32 + lh * 8;
        f32x4 p0 = *(const f32x4*)(Xf + (size_t)arc * HID + k0);
        f32x4 p1 = *(const f32x4*)(Xf + (size_t)arc * HID + k0 + 4);
        union { bf16x8 v; u16 h[8]; } au;
#pragma unroll
        for (int j = 0; j < 4; j++) { au.h[j] = f2b(p0[j]); au.h[j + 4] = f2b(p1[j]); }
        bf16x8 a = au.v;
#pragma unroll
        for (int c = 0; c < 8; c++) {
            bf16x8 b = *(const bf16x8*)(Wp + ((c * 4 + s) * 64 + l) * 8);
            acc[c] = __builtin_amdgcn_mfma_f32_16x16x32_bf16(a, b, acc[c], 0, 0, 0);
        }
    }
#pragma unroll
    for (int q = 0; q < 4; q++) {
        int row = r0 + lh * 4 + q;
        if (row < NN) {
            float dv = dinv[row];
            union { u32x4 v; u16 h[8]; } pk;
#pragma unroll
            for (int c = 0; c < 8; c++) pk.h[c] = f2b(acc[c][q] * dv);
            *(u32x4*)(Gout + (size_t)row * HID + l15 * 8) = pk.v;
        }
    }
}

// ---------------- agg1 (R6-proven): T[v] = bf16(dinv*relu(dinv*Sum + b1)) -------
__global__ __launch_bounds__(256) void k_agg1(const u16* __restrict__ g,
                                              const int* __restrict__ rp,
                                              const int* __restrict__ col,
                                              const float* __restrict__ dinv,
                                              const float* __restrict__ bias,
                                              u16* __restrict__ tout) {
    int w = threadIdx.x >> 6, l = threadIdx.x & 63;
    int v = blockIdx.x * 4 + w;
    if (v >= NN) return;
    int f0 = 2 * l;
    const u16* gl = g + f0;   // this lane's 4B column within any row

    u32 u = *(const u32*)(gl + (size_t)v * HID);   // self loop
    float a0 = blo(u), a1 = bhi(u);

    int e = rp[v], end = rp[v + 1];
    while (e < end) {
        int m = end - e; if (m > 64) m = 64;
        int ci = col[e + ((l < m) ? l : 0)];
        int j = 0;
        for (; j + 16 <= m; j += 16) {
            u32 uu[16];
#pragma unroll
            for (int k = 0; k < 16; k++) {
                int idx = __shfl(ci, j + k);
                uu[k] = *(const u32*)(gl + (size_t)idx * HID);
            }
#pragma unroll
            for (int k = 0; k < 16; k++) { a0 += blo(uu[k]); a1 += bhi(uu[k]); }
        }
        for (; j + 4 <= m; j += 4) {
            u32 uu[4];
#pragma unroll
            for (int k = 0; k < 4; k++) {
                int idx = __shfl(ci, j + k);
                uu[k] = *(const u32*)(gl + (size_t)idx * HID);
            }
#pragma unroll
            for (int k = 0; k < 4; k++) { a0 += blo(uu[k]); a1 += bhi(uu[k]); }
        }
        if (j < m) {
            int r = m - j;
            u32 uu[3];
#pragma unroll
            for (int k = 0; k < 3; k++) {
                int jk = j + k; int idx = __shfl(ci, (jk < m) ? jk : j);
                uu[k] = *(const u32*)(gl + (size_t)idx * HID);
            }
#pragma unroll
            for (int k = 0; k < 3; k++) {
                float mk = (k < r) ? 1.f : 0.f;
                a0 = fmaf(mk, blo(uu[k]), a0); a1 = fmaf(mk, bhi(uu[k]), a1);
            }
        }
        e += m;
    }

    float dv = dinv[v];
    float o0 = fmaxf(a0 * dv + bias[f0],     0.f) * dv;
    float o1 = fmaxf(a1 * dv + bias[f0 + 1], 0.f) * dv;
    u32 pk = (u32)f2b(o0) | ((u32)f2b(o1) << 16);
    int l15 = l & 15;
    u32 w0 = __shfl(pk, l15 * 4 + 0);
    u32 w1 = __shfl(pk, l15 * 4 + 1);
    u32 w2 = __shfl(pk, l15 * 4 + 2);
    u32 w3 = __shfl(pk, l15 * 4 + 3);
    if (l < 16) {
        u32x4 vv = (u32x4){w0, w1, w2, w3};
        *(u32x4*)(tout + (size_t)v * HID + l * 8) = vv;
    }
}

// ---------------- GEMM2: U = bf16(T @ Wc), [NN][64] (128B rows) ----------------
__global__ __launch_bounds__(256) void k_gemm2(const u16* __restrict__ T,
                                               const u16* __restrict__ Wcp,
                                               u16* __restrict__ U) {
    int w = threadIdx.x >> 6, l = threadIdx.x & 63;
    int r0  = blockIdx.x * 64 + w * 16;
    int l15 = l & 15, lh = l >> 4;
    int arow = r0 + l15;
    int arc  = (arow < NN) ? arow : (NN - 1);

    f32x4 acc[4];
#pragma unroll
    for (int c = 0; c < 4; c++) acc[c] = (f32x4){0.f, 0.f, 0.f, 0.f};

#pragma unroll
    for (int s = 0; s < 4; s++) {
        int k0 = s * 32 + lh * 8;
        bf16x8 a = *(const bf16x8*)(T + (size_t)arc * HID + k0);
#pragma unroll
        for (int c = 0; c < 4; c++) {
            bf16x8 b = *(const bf16x8*)(Wcp + ((c * 4 + s) * 64 + l) * 8);
            acc[c] = __builtin_amdgcn_mfma_f32_16x16x32_bf16(a, b, acc[c], 0, 0, 0);
        }
    }
#pragma unroll
    for (int q = 0; q < 4; q++) {
        int row = r0 + lh * 4 + q;
        if (row < NN) {
            union { u32x2 v; u16 h[4]; } pk;
#pragma unroll
            for (int c = 0; c < 4; c++) pk.h[c] = f2b(acc[c][q]);
            *(u32x2*)(U + (size_t)row * NOUT + l15 * 4) = pk.v;
        }
    }
}

// ---------------- agg2v: 2 nodes per wave via concatenated edge range ----------
// Wave walks [rp[v0], rp[v0+2]) (~32 edges).  Lanes 0-31 read edge 2k's 128B
// U-row, lanes 32-63 edge 2k+1's -> 16 loads x 4 lines = 64 lines in flight
// (matching agg1's depth).  Per-edge node ownership (eidx < split) steers the
// value into (a*) or (b*) accumulators via fma; cross-half shfl_xor combines.
__global__ __launch_bounds__(256) void k_agg2v(const u16* __restrict__ U,
                                               const int* __restrict__ rp,
                                               const int* __restrict__ col,
                                               const float* __restrict__ dinv,
                                               const int* __restrict__ batch,
                                               float* __restrict__ psum) {
    int w = threadIdx.x >> 6, l = threadIdx.x & 63;
    int pair = blockIdx.x * 4 + w;
    int v0 = pair * 2;
    if (v0 >= NN) return;                 // NN even -> v0+1 always valid
    int half = l >> 5, lf = l & 31;
    const u16* Ul = U + 2 * lf;           // features 2lf,2lf+1 within any 128B row

    float a0 = 0.f, a1 = 0.f, b0 = 0.f, b1 = 0.f;
    int e = rp[v0], split = rp[v0 + 1], end = rp[v0 + 2];

    while (e < end) {
        int m = end - e; if (m > 64) m = 64;
        int ci = col[e + ((l < m) ? l : 0)];
        int sp = split - e;               // edges k < sp belong to v0
        int j = 0;
        for (; j + 32 <= m; j += 32) {    // 16 unmasked loads, 32 edges
            u32 uu[16];
#pragma unroll
            for (int k = 0; k < 16; k++) {
                int idx = __shfl(ci, j + 2 * k + half);
                uu[k] = *(const u32*)(Ul + (size_t)idx * NOUT);
            }
#pragma unroll
            for (int k = 0; k < 16; k++) {
                float sA = (j + 2 * k + half < sp) ? 1.f : 0.f;
                float sB = 1.f - sA;
                float f0 = blo(uu[k]), f1 = bhi(uu[k]);
                a0 = fmaf(sA, f0, a0); a1 = fmaf(sA, f1, a1);
                b0 = fmaf(sB, f0, b0); b1 = fmaf(sB, f1, b1);
            }
        }
        for (; j < m; j += 8) {           // masked tail, 4 loads per step
            u32 uu[4];
#pragma unroll
            for (int k = 0; k < 4; k++) {
                int eidx = j + 2 * k + half;
                int idx = __shfl(ci, (eidx < m) ? eidx : 0);
                uu[k] = *(const u32*)(Ul + (size_t)idx * NOUT);
            }
#pragma unroll
            for (int k = 0; k < 4; k++) {
                int eidx = j + 2 * k + half;
                float mk = (eidx < m) ? 1.f : 0.f;
                float sA = (eidx < sp) ? mk : 0.f;
                float sB = mk - sA;
                float f0 = blo(uu[k]), f1 = bhi(uu[k]);
                a0 = fmaf(sA, f0, a0); a1 = fmaf(sA, f1, a1);
                b0 = fmaf(sB, f0, b0); b1 = fmaf(sB, f1, b1);
            }
        }
        e += m;
    }

    a0 += __shfl_xor(a0, 32); a1 += __shfl_xor(a1, 32);
    b0 += __shfl_xor(b0, 32); b1 += __shfl_xor(b1, 32);

    // self loops (post-reduce; consistent across lanes)
    u32 s0 = *(const u32*)(Ul + (size_t)v0 * NOUT);
    u32 s1 = *(const u32*)(Ul + (size_t)(v0 + 1) * NOUT);
    a0 += blo(s0); a1 += bhi(s0);
    b0 += blo(s1); b1 += bhi(s1);

    int v = v0 + half;                    // half 0 commits v0, half 1 commits v1
    float dv = dinv[v];
    float o0 = (half ? b0 : a0) * dv;
    float o1 = (half ? b1 : a1) * dv;
    float* ps = psum + (size_t)batch[v] * NOUT + 2 * lf;
    atomicAdd(ps + 0, o0);
    atomicAdd(ps + 1, o1);
}

// ---------------- final: out[g][o] = psum[g][o]/cnt + bc[o] ----------------
__global__ __launch_bounds__(256) void k_fc(const float* __restrict__ psum,
                                            const int* __restrict__ cntg,
                                            const float* __restrict__ bc,
                                            float* __restrict__ out) {
    int tid = blockIdx.x * blockDim.x + threadIdx.x;
    if (tid < NG * NOUT) {
        int gph = tid >> 6, o = tid & 63;
        float inv = 1.f / fmaxf((float)cntg[gph], 1.f);
        out[tid] = psum[tid] * inv + bc[o];
    }
}

extern "C" void kernel_launch(void* const* d_in, const int* in_sizes, int n_in,
                              void* d_out, int out_size, void* d_ws, size_t ws_size,
                              hipStream_t stream) {
    const float* x     = (const float*)d_in[0];
    const int*   ei    = (const int*)d_in[1];
    const int*   batch = (const int*)d_in[3];
    const float* W1    = (const float*)d_in[4];
    const float* b1    = (const float*)d_in[5];
    const float* W2    = (const float*)d_in[6];
    const float* b2    = (const float*)d_in[7];
    const float* Wfc   = (const float*)d_in[8];
    const float* bfc   = (const float*)d_in[9];
    float* out = (float*)d_out;

    const int* src = ei;
    const int* dst = ei + NE;

    char* p = (char*)d_ws;
    auto take = [&](size_t bytes) { char* r = p; p += (bytes + 255) & ~(size_t)255; return r; };
    // zero-group (one memset covers bcnt..psum)
    int*   bcnt = (int*)take((size_t)NBUK * 4);
    int*   cntg = (int*)take((size_t)NG * 4);
    float* psum = (float*)take((size_t)NG * NOUT * 4);
    size_t zspan = (size_t)((char*)psum + (size_t)NG * NOUT * 4 - (char*)bcnt);
    int*   boff = (int*)take((size_t)(NBUK + 1) * 4);
    int*   gcur = (int*)take((size_t)NBUK * 4);
    int*   rp   = (int*)take((size_t)(NN + 1) * 4);
    float* dinv = (float*)take((size_t)NN * 4);
    u16*   Wp1  = (u16*)take((size_t)32 * 64 * 8 * 2);
    u16*   Wcp  = (u16*)take((size_t)16 * 64 * 8 * 2);
    float* bc   = (float*)take((size_t)NOUT * 4);
    int*   col  = (int*)take((size_t)NE * 4);
    u16*   g    = (u16*)take((size_t)NN * HID * 2);
    u16*   t    = (u16*)take((size_t)NN * HID * 2);
    u16*   U    = (u16*)take((size_t)NN * NOUT * 2);
    EdgeT* ebuf = (EdgeT*)g;   // aliased: ebuf consumed by k_bucketc before k_gemm writes g

    hipMemsetAsync(bcnt, 0, zspan, stream);

    k_bhist  <<<NAH, 256, 0, stream>>>(dst, bcnt);
    k_bscan  <<<1, 256, 0, stream>>>(bcnt, boff, gcur, rp + NN);
    k_scatter<<<NSC, 256, 0, stream>>>(src, dst, gcur, ebuf);
    k_bucketc<<<NBUK, 256, 0, stream>>>(ebuf, boff, rp, dinv, col);
    k_wprep  <<<(2048 + HID * NOUT + NOUT + NG + 255) / 256, 256, 0, stream>>>
             (W1, Wp1, W2, Wfc, b2, bfc, Wcp, bc, batch, cntg);

    k_gemm   <<<(NN + 63) / 64, 256, 0, stream>>>(x, Wp1, dinv, g);
    k_agg1   <<<(NN + 3) / 4, 256, 0, stream>>>(g, rp, col, dinv, b1, t);
    k_gemm2  <<<(NN + 63) / 64, 256, 0, stream>>>(t, Wcp, U);
    k_agg2v  <<<(NN / 2 + 3) / 4, 256, 0, stream>>>(U, rp, col, dinv, batch, psum);
    k_fc     <<<(NG * NOUT + 255) / 256, 256, 0, stream>>>(psum, cntg, bc, out);
}

// Round 19
// 241.078 us; speedup vs baseline: 1.1897x; 1.1897x over previous
//
#include <hip/hip_runtime.h>
#include <stdint.h>

#define NN   100000
#define NE   1600000
#define NG   512
#define HID  128
#define NOUT 64
#define BK   128
#define BKSH 7
#define NBUK ((NN + BK - 1) / BK)      // 782 buckets of 128 nodes
#define AHIST_E 4096
#define NAH  ((NE + AHIST_E - 1) / AHIST_E)   // 391
#define CHUNK 8192
#define NSC  ((NE + CHUNK - 1) / CHUNK)       // 196

typedef __bf16 bf16_t;
typedef bf16_t bf16x8 __attribute__((ext_vector_type(8)));
typedef float  f32x4  __attribute__((ext_vector_type(4)));
typedef unsigned int u32;
typedef u32 u32x2 __attribute__((ext_vector_type(2)));
typedef u32 u32x4 __attribute__((ext_vector_type(4)));
typedef unsigned short u16;

struct __align__(8) EdgeT { int d, s; };

__device__ __forceinline__ u16 f2b(float f) {
    union { float f; u32 u; } v; v.f = f;
    u32 u = v.u + 0x7fffu + ((v.u >> 16) & 1u);   // RNE
    return (u16)(u >> 16);
}
__device__ __forceinline__ float blo(u32 u) {
    union { u32 u; float f; } v; v.u = u << 16; return v.f;
}
__device__ __forceinline__ float bhi(u32 u) {
    union { u32 u; float f; } v; v.u = u & 0xffff0000u; return v.f;
}

// ---------------- CSR build, bucketed (BK=128) ----------------
__global__ __launch_bounds__(256) void k_bhist(const int* __restrict__ dst,
                                               int* __restrict__ bcnt) {
    __shared__ int h[NBUK];
    int t = threadIdx.x;
    for (int i = t; i < NBUK; i += 256) h[i] = 0;
    __syncthreads();
    int e0 = blockIdx.x * AHIST_E;
    int e1 = min(NE, e0 + AHIST_E);
    for (int e = e0 + t; e < e1; e += 256) atomicAdd(&h[dst[e] >> BKSH], 1);
    __syncthreads();
    for (int i = t; i < NBUK; i += 256) if (h[i]) atomicAdd(&bcnt[i], h[i]);
}

// scan of NBUK (<=1024) bucket counts: 4 elements per thread
__global__ __launch_bounds__(256) void k_bscan(const int* __restrict__ bcnt,
                                               int* __restrict__ boff, int* __restrict__ gcur,
                                               int* __restrict__ rpN) {
    __shared__ int sh[256];
    int t = threadIdx.x;
    int v[4]; int s = 0;
#pragma unroll
    for (int j = 0; j < 4; j++) {
        int idx = t * 4 + j;
        v[j] = (idx < NBUK) ? bcnt[idx] : 0;
        s += v[j];
    }
    sh[t] = s; __syncthreads();
    for (int off = 1; off < 256; off <<= 1) {
        int x = (t >= off) ? sh[t - off] : 0;
        __syncthreads();
        sh[t] += x;
        __syncthreads();
    }
    int run = sh[t] - s;
#pragma unroll
    for (int j = 0; j < 4; j++) {
        int idx = t * 4 + j;
        if (idx < NBUK) { boff[idx] = run; gcur[idx] = run; }
        run += v[j];
    }
    if (t == 255) { boff[NBUK] = NE; rpN[0] = NE; }
}

__global__ __launch_bounds__(256) void k_scatter(const int* __restrict__ src,
                                                 const int* __restrict__ dst,
                                                 int* __restrict__ gcur,
                                                 EdgeT* __restrict__ ebuf) {
    __shared__ int hist[NBUK], base[NBUK];
    int t = threadIdx.x;
    for (int i = t; i < NBUK; i += 256) hist[i] = 0;
    __syncthreads();
    int e0 = blockIdx.x * CHUNK;
    int e1 = min(NE, e0 + CHUNK);
    for (int e = e0 + t; e < e1; e += 256) atomicAdd(&hist[dst[e] >> BKSH], 1);
    __syncthreads();
    for (int i = t; i < NBUK; i += 256) {
        int h = hist[i];
        base[i] = h ? atomicAdd(&gcur[i], h) : 0;
        hist[i] = 0;
    }
    __syncthreads();
    for (int e = e0 + t; e < e1; e += 256) {
        int d = dst[e], bk = d >> BKSH;
        int r = atomicAdd(&hist[bk], 1);
        EdgeT p; p.d = d; p.s = src[e];
        ebuf[base[bk] + r] = p;
    }
}

// cntg via binary search on sorted batch (replaces 100K contended global atomics)
__global__ __launch_bounds__(512) void k_cntg(const int* __restrict__ batch,
                                              int* __restrict__ cntg) {
    int g = threadIdx.x;
    int lo0 = 0, hi0 = NN;
    while (lo0 < hi0) { int mid = (lo0 + hi0) >> 1; if (batch[mid] < g) lo0 = mid + 1; else hi0 = mid; }
    int lo1 = lo0, hi1 = NN;
    while (lo1 < hi1) { int mid = (lo1 + hi1) >> 1; if (batch[mid] < g + 1) lo1 = mid + 1; else hi1 = mid; }
    cntg[g] = lo1 - lo0;
}

__global__ __launch_bounds__(256) void k_bucketc(const EdgeT* __restrict__ ebuf,
                                                 const int* __restrict__ boff,
                                                 int* __restrict__ rp, float* __restrict__ dinv,
                                                 int* __restrict__ col) {
    __shared__ int cnt[BK], pos[BK], run[BK], s2[64];
    int b = blockIdx.x, t = threadIdx.x;
    int d0 = b * BK;
    int e0 = boff[b], e1 = boff[b + 1];
    for (int i = t; i < BK; i += 256) { cnt[i] = 0; run[i] = 0; }
    __syncthreads();
    for (int e = e0 + t; e < e1; e += 256) atomicAdd(&cnt[ebuf[e].d - d0], 1);
    __syncthreads();
    for (int i = t; i < BK; i += 256) {
        int v = d0 + i;
        if (v < NN) dinv[v] = rsqrtf((float)(cnt[i] + 1));
    }
    // exclusive scan of cnt[0..127] via 64-thread pair-sum
    int c0 = 0, c1 = 0, s = 0;
    if (t < 64) {
        c0 = cnt[2 * t]; c1 = cnt[2 * t + 1];
        s = c0 + c1; s2[t] = s;
    }
    __syncthreads();
    for (int off = 1; off < 64; off <<= 1) {
        int x = (t >= off && t < 64) ? s2[t - off] : 0;
        __syncthreads();
        if (t < 64) s2[t] += x;
        __syncthreads();
    }
    if (t < 64) {
        int bse = s2[t] - s;
        pos[2 * t] = bse; pos[2 * t + 1] = bse + c0;
    }
    __syncthreads();
    for (int i = t; i < BK; i += 256) {
        int v = d0 + i;
        if (v < NN) rp[v] = e0 + pos[i];
    }
    for (int e = e0 + t; e < e1; e += 256) {
        EdgeT p = ebuf[e];
        int i = p.d - d0;
        int r = atomicAdd(&run[i], 1);
        col[e0 + pos[i] + r] = p.s;
    }
}

// ---------------- fused weight prep (R11-proven) ----------------
__global__ void k_wprep(const float* __restrict__ W1, u16* __restrict__ Wp,
                        const float* __restrict__ W2, const float* __restrict__ Wfc,
                        const float* __restrict__ b2, const float* __restrict__ bfc,
                        u16* __restrict__ Wcp, float* __restrict__ bc) {
    int tid = blockIdx.x * blockDim.x + threadIdx.x;
    if (tid < 2048) {
        int f = tid >> 6, l = tid & 63;
        int c = f >> 2, s = f & 3;
        int n  = (l & 15) * 8 + c;
        int k0 = s * 32 + ((l >> 4) << 3);
#pragma unroll
        for (int j = 0; j < 8; j++) Wp[tid * 8 + j] = f2b(W1[(k0 + j) * HID + n]);
    } else if (tid < 2048 + HID * NOUT) {
        int t2 = tid - 2048;
        int k = t2 >> 6, n = t2 & 63;
        float a = 0.f;
        for (int m = 0; m < HID; m++) a += W2[k * HID + m] * Wfc[m * NOUT + n];
        int s = k >> 5, lh = (k >> 3) & 3, j = k & 7;
        int c = n & 3, l15 = n >> 2;
        int l = (lh << 4) | l15, f = c * 4 + s;
        Wcp[((f * 64 + l) << 3) + j] = f2b(a);
    } else if (tid < 2048 + HID * NOUT + NOUT) {
        int o = tid - 2048 - HID * NOUT;
        float a = bfc[o];
        for (int k = 0; k < HID; k++) a += b2[k] * Wfc[k * NOUT + o];
        bc[o] = a;
    }
}

// ---------------- GEMM1: g = bf16((X @ W1) * dinv[row]), [NN][128] ----------------
__global__ __launch_bounds__(256) void k_gemm(const float* __restrict__ Xf,
                                              const u16* __restrict__ Wp,
                                              const float* __restrict__ dinv,
                                              u16* __restrict__ Gout) {
    int w = threadIdx.x >> 6, l = threadIdx.x & 63;
    int r0  = blockIdx.x * 64 + w * 16;
    int l15 = l & 15, lh = l >> 4;
    int arow = r0 + l15;
    int arc  = (arow < NN) ? arow : (NN - 1);

    f32x4 acc[8];
#pragma unroll
    for (int c = 0; c < 8; c++) acc[c] = (f32x4){0.f, 0.f, 0.f, 0.f};

#pragma unroll
    for (int s = 0; s < 4; s++) {
        int k0 = s * 32 + lh * 8;
        f32x4 p0 = *(const f32x4*)(Xf + (size_t)arc * HID + k0);
        f32x4 p1 = *(const f32x4*)(Xf + (size_t)arc * HID + k0 + 4);
        union { bf16x8 v; u16 h[8]; } au;
#pragma unroll
        for (int j = 0; j < 4; j++) { au.h[j] = f2b(p0[j]); au.h[j + 4] = f2b(p1[j]); }
        bf16x8 a = au.v;
#pragma unroll
        for (int c = 0; c < 8; c++) {
            bf16x8 b = *(const bf16x8*)(Wp + ((c * 4 + s) * 64 + l) * 8);
            acc[c] = __builtin_amdgcn_mfma_f32_16x16x32_bf16(a, b, acc[c], 0, 0, 0);
        }
    }
#pragma unroll
    for (int q = 0; q < 4; q++) {
        int row = r0 + lh * 4 + q;
        if (row < NN) {
            float dv = dinv[row];
            union { u32x4 v; u16 h[8]; } pk;
#pragma unroll
            for (int c = 0; c < 8; c++) pk.h[c] = f2b(acc[c][q] * dv);
            *(u32x4*)(Gout + (size_t)row * HID + l15 * 8) = pk.v;
        }
    }
}

// ---------------- agg1 (R6-proven): T[v] = bf16(dinv*relu(dinv*Sum + b1)) -------
__global__ __launch_bounds__(256) void k_agg1(const u16* __restrict__ g,
                                              const int* __restrict__ rp,
                                              const int* __restrict__ col,
                                              const float* __restrict__ dinv,
                                              const float* __restrict__ bias,
                                              u16* __restrict__ tout) {
    int w = threadIdx.x >> 6, l = threadIdx.x & 63;
    int v = blockIdx.x * 4 + w;
    if (v >= NN) return;
    int f0 = 2 * l;
    const u16* gl = g + f0;   // this lane's 4B column within any row

    u32 u = *(const u32*)(gl + (size_t)v * HID);   // self loop
    float a0 = blo(u), a1 = bhi(u);

    int e = rp[v], end = rp[v + 1];
    while (e < end) {
        int m = end - e; if (m > 64) m = 64;
        int ci = col[e + ((l < m) ? l : 0)];
        int j = 0;
        for (; j + 16 <= m; j += 16) {
            u32 uu[16];
#pragma unroll
            for (int k = 0; k < 16; k++) {
                int idx = __shfl(ci, j + k);
                uu[k] = *(const u32*)(gl + (size_t)idx * HID);
            }
#pragma unroll
            for (int k = 0; k < 16; k++) { a0 += blo(uu[k]); a1 += bhi(uu[k]); }
        }
        for (; j + 4 <= m; j += 4) {
            u32 uu[4];
#pragma unroll
            for (int k = 0; k < 4; k++) {
                int idx = __shfl(ci, j + k);
                uu[k] = *(const u32*)(gl + (size_t)idx * HID);
            }
#pragma unroll
            for (int k = 0; k < 4; k++) { a0 += blo(uu[k]); a1 += bhi(uu[k]); }
        }
        if (j < m) {
            int r = m - j;
            u32 uu[3];
#pragma unroll
            for (int k = 0; k < 3; k++) {
                int jk = j + k; int idx = __shfl(ci, (jk < m) ? jk : j);
                uu[k] = *(const u32*)(gl + (size_t)idx * HID);
            }
#pragma unroll
            for (int k = 0; k < 3; k++) {
                float mk = (k < r) ? 1.f : 0.f;
                a0 = fmaf(mk, blo(uu[k]), a0); a1 = fmaf(mk, bhi(uu[k]), a1);
            }
        }
        e += m;
    }

    float dv = dinv[v];
    float o0 = fmaxf(a0 * dv + bias[f0],     0.f) * dv;
    float o1 = fmaxf(a1 * dv + bias[f0 + 1], 0.f) * dv;
    u32 pk = (u32)f2b(o0) | ((u32)f2b(o1) << 16);
    int l15 = l & 15;
    u32 w0 = __shfl(pk, l15 * 4 + 0);
    u32 w1 = __shfl(pk, l15 * 4 + 1);
    u32 w2 = __shfl(pk, l15 * 4 + 2);
    u32 w3 = __shfl(pk, l15 * 4 + 3);
    if (l < 16) {
        u32x4 vv = (u32x4){w0, w1, w2, w3};
        *(u32x4*)(tout + (size_t)v * HID + l * 8) = vv;
    }
}

// ---------------- GEMM2: U = bf16(T @ Wc), [NN][64] (128B rows) ----------------
__global__ __launch_bounds__(256) void k_gemm2(const u16* __restrict__ T,
                                               const u16* __restrict__ Wcp,
                                               u16* __restrict__ U) {
    int w = threadIdx.x >> 6, l = threadIdx.x & 63;
    int r0  = blockIdx.x * 64 + w * 16;
    int l15 = l & 15, lh = l >> 4;
    int arow = r0 + l15;
    int arc  = (arow < NN) ? arow : (NN - 1);

    f32x4 acc[4];
#pragma unroll
    for (int c = 0; c < 4; c++) acc[c] = (f32x4){0.f, 0.f, 0.f, 0.f};

#pragma unroll
    for (int s = 0; s < 4; s++) {
        int k0 = s * 32 + lh * 8;
        bf16x8 a = *(const bf16x8*)(T + (size_t)arc * HID + k0);
#pragma unroll
        for (int c = 0; c < 4; c++) {
            bf16x8 b = *(const bf16x8*)(Wcp + ((c * 4 + s) * 64 + l) * 8);
            acc[c] = __builtin_amdgcn_mfma_f32_16x16x32_bf16(a, b, acc[c], 0, 0, 0);
        }
    }
#pragma unroll
    for (int q = 0; q < 4; q++) {
        int row = r0 + lh * 4 + q;
        if (row < NN) {
            union { u32x2 v; u16 h[4]; } pk;
#pragma unroll
            for (int c = 0; c < 4; c++) pk.h[c] = f2b(acc[c][q]);
            *(u32x2*)(U + (size_t)row * NOUT + l15 * 4) = pk.v;
        }
    }
}

// ---------------- agg2u: R6-shape walk over U, one u16 per lane ----------------
__global__ __launch_bounds__(256) void k_agg2u(const u16* __restrict__ U,
                                               const int* __restrict__ rp,
                                               const int* __restrict__ col,
                                               const float* __restrict__ dinv,
                                               const int* __restrict__ batch,
                                               float* __restrict__ psum) {
    int w = threadIdx.x >> 6, l = threadIdx.x & 63;
    int v = blockIdx.x * 4 + w;
    if (v >= NN) return;
    const u16* Ul = U + l;    // this lane's 2B column within any 128B row

    float a0 = blo((u32)Ul[(size_t)v * NOUT]);     // self loop

    int e = rp[v], end = rp[v + 1];
    while (e < end) {
        int m = end - e; if (m > 64) m = 64;
        int ci = col[e + ((l < m) ? l : 0)];
        int j = 0;
        for (; j + 16 <= m; j += 16) {
            u16 uu[16];
#pragma unroll
            for (int k = 0; k < 16; k++) {
                int idx = __shfl(ci, j + k);
                uu[k] = Ul[(size_t)idx * NOUT];
            }
#pragma unroll
            for (int k = 0; k < 16; k++) a0 += blo((u32)uu[k]);
        }
        for (; j + 4 <= m; j += 4) {
            u16 uu[4];
#pragma unroll
            for (int k = 0; k < 4; k++) {
                int idx = __shfl(ci, j + k);
                uu[k] = Ul[(size_t)idx * NOUT];
            }
#pragma unroll
            for (int k = 0; k < 4; k++) a0 += blo((u32)uu[k]);
        }
        if (j < m) {
            int r = m - j;
            u16 uu[3];
#pragma unroll
            for (int k = 0; k < 3; k++) {
                int jk = j + k; int idx = __shfl(ci, (jk < m) ? jk : j);
                uu[k] = Ul[(size_t)idx * NOUT];
            }
#pragma unroll
            for (int k = 0; k < 3; k++) {
                float mk = (k < r) ? 1.f : 0.f;
                a0 = fmaf(mk, blo((u32)uu[k]), a0);
            }
        }
        e += m;
    }

    atomicAdd(&psum[(size_t)batch[v] * NOUT + l], a0 * dinv[v]);
}

// ---------------- final: out[g][o] = psum[g][o]/cnt + bc[o] ----------------
__global__ __launch_bounds__(256) void k_fc(const float* __restrict__ psum,
                                            const int* __restrict__ cntg,
                                            const float* __restrict__ bc,
                                            float* __restrict__ out) {
    int tid = blockIdx.x * blockDim.x + threadIdx.x;
    if (tid < NG * NOUT) {
        int gph = tid >> 6, o = tid & 63;
        float inv = 1.f / fmaxf((float)cntg[gph], 1.f);
        out[tid] = psum[tid] * inv + bc[o];
    }
}

extern "C" void kernel_launch(void* const* d_in, const int* in_sizes, int n_in,
                              void* d_out, int out_size, void* d_ws, size_t ws_size,
                              hipStream_t stream) {
    const float* x     = (const float*)d_in[0];
    const int*   ei    = (const int*)d_in[1];
    const int*   batch = (const int*)d_in[3];
    const float* W1    = (const float*)d_in[4];
    const float* b1    = (const float*)d_in[5];
    const float* W2    = (const float*)d_in[6];
    const float* b2    = (const float*)d_in[7];
    const float* Wfc   = (const float*)d_in[8];
    const float* bfc   = (const float*)d_in[9];
    float* out = (float*)d_out;

    const int* src = ei;
    const int* dst = ei + NE;

    char* p = (char*)d_ws;
    auto take = [&](size_t bytes) { char* r = p; p += (bytes + 255) & ~(size_t)255; return r; };
    // zero-group (one memset covers bcnt..psum)
    int*   bcnt = (int*)take((size_t)NBUK * 4);
    int*   cntg = (int*)take((size_t)NG * 4);
    float* psum = (float*)take((size_t)NG * NOUT * 4);
    size_t zspan = (size_t)((char*)psum + (size_t)NG * NOUT * 4 - (char*)bcnt);
    int*   boff = (int*)take((size_t)(NBUK + 1) * 4);
    int*   gcur = (int*)take((size_t)NBUK * 4);
    int*   rp   = (int*)take((size_t)(NN + 1) * 4);
    float* dinv = (float*)take((size_t)NN * 4);
    u16*   Wp1  = (u16*)take((size_t)32 * 64 * 8 * 2);
    u16*   Wcp  = (u16*)take((size_t)16 * 64 * 8 * 2);
    float* bc   = (float*)take((size_t)NOUT * 4);
    int*   col  = (int*)take((size_t)NE * 4);
    u16*   g    = (u16*)take((size_t)NN * HID * 2);
    u16*   t    = (u16*)take((size_t)NN * HID * 2);
    u16*   U    = (u16*)take((size_t)NN * NOUT * 2);
    EdgeT* ebuf = (EdgeT*)g;   // aliased: ebuf consumed by k_bucketc before k_gemm writes g

    hipMemsetAsync(bcnt, 0, zspan, stream);

    k_bhist  <<<NAH, 256, 0, stream>>>(dst, bcnt);
    k_bscan  <<<1, 256, 0, stream>>>(bcnt, boff, gcur, rp + NN);
    k_scatter<<<NSC, 256, 0, stream>>>(src, dst, gcur, ebuf);
    k_bucketc<<<NBUK, 256, 0, stream>>>(ebuf, boff, rp, dinv, col);
    k_cntg   <<<1, 512, 0, stream>>>(batch, cntg);
    k_wprep  <<<(2048 + HID * NOUT + NOUT + 255) / 256, 256, 0, stream>>>
             (W1, Wp1, W2, Wfc, b2, bfc, Wcp, bc);

    k_gemm   <<<(NN + 63) / 64, 256, 0, stream>>>(x, Wp1, dinv, g);
    k_agg1   <<<(NN + 3) / 4, 256, 0, stream>>>(g, rp, col, dinv, b1, t);
    k_gemm2  <<<(NN + 63) / 64, 256, 0, stream>>>(t, Wcp, U);
    k_agg2u  <<<(NN + 3) / 4, 256, 0, stream>>>(U, rp, col, dinv, batch, psum);
    k_fc     <<<(NG * NOUT + 255) / 256, 256, 0, stream>>>(psum, cntg, bc, out);
}